// Round 4
// baseline (42.209 us; speedup 1.0000x reference)
//
#include <hip/hip_runtime.h>
#include <float.h>

typedef __attribute__((ext_vector_type(8))) short short8;
typedef __attribute__((ext_vector_type(4))) float f32x4;

#define SLOPE 0.2f
// leaky(t) = 0.6t + 0.4|t| for slope 0.2

__device__ __forceinline__ float leaky(float x) { return fmaxf(x, SLOPE * x); }

// f32 -> bf16 round-to-nearest-even
__device__ __forceinline__ unsigned short f2bf(float f) {
  unsigned u = __float_as_uint(f);
  return (unsigned short)((u + 0x7FFFu + ((u >> 16) & 1u)) >> 16);
}

// ---------------------------------------------------------------------------
// Kernel A: per-node MLPs + projections + rank-1 score terms + transposed
// outputs for kernel B:
//   ss   = self_e @ comb_w1[:64] + comb_b1          (row-major, s_load rows)
//   snT[b][k][j] = (nb_e @ comb_w1[64:])[j][k]      (coalesced per-lane j)
//   sP   = 0.6*sum_k(w2_k*ss_k) + comb_b2 ; sQ = 0.6*sum_k(w2_k*sn_k)
//   nbT[b][h][j] = bf16(nb_e[b][j][h])              (MFMA B-operand layout)
// 512 blocks x 256 thr; 8 nodes/block; each wave owns 2 nodes.
// ---------------------------------------------------------------------------
__global__ __launch_bounds__(256) void node_mlps(
    const float* __restrict__ nodes,
    const float* __restrict__ self_w1, const float* __restrict__ self_b1,
    const float* __restrict__ self_w2, const float* __restrict__ self_b2,
    const float* __restrict__ nb_w1,   const float* __restrict__ nb_b1,
    const float* __restrict__ nb_w2,   const float* __restrict__ nb_b2,
    const float* __restrict__ comb_w1, const float* __restrict__ comb_b1,
    const float* __restrict__ comb_w2, const float* __restrict__ comb_b2,
    float* __restrict__ self_e,
    float* __restrict__ ss, float* __restrict__ snT,
    float* __restrict__ sP, float* __restrict__ sQ,
    unsigned short* __restrict__ nbT)
{
  __shared__ float x_sh[8][128];
  __shared__ float h_sh[8][64];
  __shared__ float e_sh[8][64];

  const int tid = threadIdx.x, lane = tid & 63, wv = tid >> 6;
  const int node0 = blockIdx.x * 8;
  const int bb = node0 >> 9;          // batch
  const int jloc = node0 & 511;       // batch-local node base

  ((float4*)&x_sh[0][0])[tid] = ((const float4*)(nodes + (size_t)node0 * 128))[tid];
  __syncthreads();

  const int la = wv * 2, lb = la + 1;
  const float w2lane = comb_w2[lane];
  const float cb2 = comb_b2[0];
  const float cb1 = comb_b1[lane];

  for (int p = 0; p < 2; ++p) {
    const float* w1 = p ? nb_w1 : self_w1;
    const float* b1 = p ? nb_b1 : self_b1;
    const float* w2 = p ? nb_w2 : self_w2;
    const float* b2 = p ? nb_b2 : self_b2;
    const float* cw = comb_w1 + (p ? 64 * 64 : 0);

    // ---- layer 1 ----
    float a0 = 0.f, a1 = 0.f, c0 = 0.f, c1 = 0.f;
    #pragma unroll 4
    for (int q = 0; q < 32; ++q) {
      float4 xa = *(const float4*)&x_sh[la][q * 4];
      float4 xb = *(const float4*)&x_sh[lb][q * 4];
      float w_0 = w1[(q * 4 + 0) * 64 + lane];
      float w_1 = w1[(q * 4 + 1) * 64 + lane];
      float w_2 = w1[(q * 4 + 2) * 64 + lane];
      float w_3 = w1[(q * 4 + 3) * 64 + lane];
      a0 += xa.x * w_0; a1 += xa.y * w_1; a0 += xa.z * w_2; a1 += xa.w * w_3;
      c0 += xb.x * w_0; c1 += xb.y * w_1; c0 += xb.z * w_2; c1 += xb.w * w_3;
    }
    {
      float bv = b1[lane];
      h_sh[la][lane] = leaky(a0 + a1 + bv);
      h_sh[lb][lane] = leaky(c0 + c1 + bv);
    }
    __syncthreads();

    // ---- layer 2 ----
    a0 = a1 = c0 = c1 = 0.f;
    #pragma unroll 4
    for (int q = 0; q < 16; ++q) {
      float4 ha = *(const float4*)&h_sh[la][q * 4];
      float4 hb = *(const float4*)&h_sh[lb][q * 4];
      float w_0 = w2[(q * 4 + 0) * 64 + lane];
      float w_1 = w2[(q * 4 + 1) * 64 + lane];
      float w_2 = w2[(q * 4 + 2) * 64 + lane];
      float w_3 = w2[(q * 4 + 3) * 64 + lane];
      a0 += ha.x * w_0; a1 += ha.y * w_1; a0 += ha.z * w_2; a1 += ha.w * w_3;
      c0 += hb.x * w_0; c1 += hb.y * w_1; c0 += hb.z * w_2; c1 += hb.w * w_3;
    }
    float e_a, e_b;
    {
      float bv = b2[lane];
      e_a = a0 + a1 + bv;
      e_b = c0 + c1 + bv;
    }
    e_sh[la][lane] = e_a;
    e_sh[lb][lane] = e_b;
    if (p == 0) {
      self_e[(size_t)(node0 + la) * 64 + lane] = e_a;
      self_e[(size_t)(node0 + lb) * 64 + lane] = e_b;
    }
    __syncthreads();

    // ---- projection ----
    a0 = a1 = c0 = c1 = 0.f;
    #pragma unroll 4
    for (int q = 0; q < 16; ++q) {
      float4 ea = *(const float4*)&e_sh[la][q * 4];
      float4 eb = *(const float4*)&e_sh[lb][q * 4];
      float w_0 = cw[(q * 4 + 0) * 64 + lane];
      float w_1 = cw[(q * 4 + 1) * 64 + lane];
      float w_2 = cw[(q * 4 + 2) * 64 + lane];
      float w_3 = cw[(q * 4 + 3) * 64 + lane];
      a0 += ea.x * w_0; a1 += ea.y * w_1; a0 += ea.z * w_2; a1 += ea.w * w_3;
      c0 += eb.x * w_0; c1 += eb.y * w_1; c0 += eb.z * w_2; c1 += eb.w * w_3;
    }
    float s_a = a0 + a1 + (p ? 0.f : cb1);
    float s_b = c0 + c1 + (p ? 0.f : cb1);
    if (p == 0) {
      ss[(size_t)(node0 + la) * 64 + lane] = s_a;
      ss[(size_t)(node0 + lb) * 64 + lane] = s_b;
    } else {
      // snT[b][k=lane][j]
      *(float2*)(snT + ((size_t)(bb * 64 + lane)) * 512 + jloc + la) =
          make_float2(s_a, s_b);
    }
    float ra = w2lane * s_a, rb = w2lane * s_b;
    #pragma unroll
    for (int off = 32; off; off >>= 1) {
      ra += __shfl_xor(ra, off);
      rb += __shfl_xor(rb, off);
    }
    if (lane == 0) {
      float* po = p ? sQ : sP;
      float add = p ? 0.f : cb2;
      po[node0 + la] = 0.6f * ra + add;
      po[node0 + lb] = 0.6f * rb + add;
    }

    if (p == 1) {
      // nbT[b][h=lane][j]
      float v0 = e_sh[la][lane];
      float v1 = e_sh[lb][lane];
      unsigned pack = (unsigned)f2bf(v0) | ((unsigned)f2bf(v1) << 16);
      *(unsigned*)(nbT + ((size_t)(bb * 64 + lane) * 512 + jloc + la)) = pack;
    }
    __syncthreads();
  }
}

// ---------------------------------------------------------------------------
// Kernel B: 256 blocks (b = blk&7), 16 rows/block, 512 thr (8 waves).
// Lane owns column j = wv*64+lane: sn[j][*] in 64 VGPRs, ss rows via
// wave-uniform loads, scores/mask/exp fully in registers. Softmax via
// shfl + tiny cross-wave LDS reduce. MFMA aggregation (verified mapping):
// wave = (nt = wv&3, kh = wv>>2), D = P(16x512)@nbT(512x64) in bf16.
// ---------------------------------------------------------------------------
__global__ __launch_bounds__(512) void gat_attn(
    const int* __restrict__ edges,
    const float* __restrict__ comb_w2,
    const float* __restrict__ self_e,
    const float* __restrict__ ss, const float* __restrict__ snT,
    const float* __restrict__ sP, const float* __restrict__ sQ,
    const unsigned short* __restrict__ nbT,
    float* __restrict__ out)
{
  __shared__ __align__(16) unsigned short P_sh[16][520];    // 16.6 KB
  __shared__ __align__(16) unsigned short nbT_sh[64][520];  // 66.6 KB
  __shared__ __align__(16) float red_sh[4][64][4];          // 4 KB
  __shared__ float rmax_sh[8][16];
  __shared__ float rsum_sh[8][16];
  __shared__ float mx_sh[16];
  __shared__ float f_sh[16];

  const int tid = threadIdx.x, lane = tid & 63, wv = tid >> 6;
  const int blk = blockIdx.x;
  const int b = blk & 7, it = blk >> 3;
  const int i0 = it * 16;
  const size_t nodeb = (size_t)b * 512;
  const int j = wv * 64 + lane;       // owned batch-local column

  // ---- stage nbT -> LDS (8 rows/wave, coalesced; consumed after B2) ----
  #pragma unroll
  for (int r8 = 0; r8 < 8; ++r8) {
    const int r = wv * 8 + r8;
    short8 v = *(const short8*)(nbT + ((size_t)(b * 64 + r)) * 512 + lane * 8);
    *(short8*)&nbT_sh[r][lane * 8] = v;
  }

  // ---- per-lane register state ----
  float snv[64];
  #pragma unroll
  for (int k = 0; k < 64; ++k)
    snv[k] = snT[((size_t)(b * 64 + k)) * 512 + j];

  float w2p[64];
  #pragma unroll
  for (int k = 0; k < 64; ++k) w2p[k] = 0.4f * comb_w2[k];

  const float sQj = sQ[nodeb + j];

  unsigned emask = 0;
  {
    const int* er = edges + ((size_t)(nodeb + j)) * 512 + i0;
    #pragma unroll
    for (int c = 0; c < 4; ++c) {
      int4 e4 = *(const int4*)(er + c * 4);
      emask |= (e4.x != 0 ? 1u : 0u) << (c * 4 + 0);
      emask |= (e4.y != 0 ? 1u : 0u) << (c * 4 + 1);
      emask |= (e4.z != 0 ? 1u : 0u) << (c * 4 + 2);
      emask |= (e4.w != 0 ? 1u : 0u) << (c * 4 + 3);
    }
    const int d = j - i0;
    if (d >= 0 && d < 16) emask &= ~(1u << d);  // no self-loop
  }

  // ---- scores: msc[i] for this lane's j ----
  float msc[16];
  #pragma unroll
  for (int i = 0; i < 16; ++i) {
    const float4* srow = (const float4*)(ss + (nodeb + i0 + i) * 64);
    float a0 = 0.f, a1 = 0.f;
    #pragma unroll
    for (int q = 0; q < 16; ++q) {
      float4 s4 = srow[q];
      a0 += w2p[q * 4 + 0] * fabsf(s4.x + snv[q * 4 + 0]);
      a1 += w2p[q * 4 + 1] * fabsf(s4.y + snv[q * 4 + 1]);
      a0 += w2p[q * 4 + 2] * fabsf(s4.z + snv[q * 4 + 2]);
      a1 += w2p[q * 4 + 3] * fabsf(s4.w + snv[q * 4 + 3]);
    }
    const float sc = a0 + a1 + sP[nodeb + i0 + i] + sQj;
    msc[i] = ((emask >> i) & 1u) ? sc : -FLT_MAX;
  }

  // ---- per-wave partial max ----
  #pragma unroll
  for (int i = 0; i < 16; ++i) {
    float v = msc[i];
    #pragma unroll
    for (int off = 32; off; off >>= 1) v = fmaxf(v, __shfl_xor(v, off));
    if (lane == 0) rmax_sh[wv][i] = v;
  }
  __syncthreads();                    // B1
  if (tid < 16) {
    float m = rmax_sh[0][tid];
    #pragma unroll
    for (int w = 1; w < 8; ++w) m = fmaxf(m, rmax_sh[w][tid]);
    mx_sh[tid] = m;
  }
  __syncthreads();                    // B2

  // ---- exp + bf16 P write + per-wave partial sum ----
  #pragma unroll
  for (int i = 0; i < 16; ++i) {
    const float e = __expf(msc[i] - mx_sh[i]);
    P_sh[i][j] = f2bf(e);
    float v = e;
    #pragma unroll
    for (int off = 32; off; off >>= 1) v += __shfl_xor(v, off);
    if (lane == 0) rsum_sh[wv][i] = v;
  }
  __syncthreads();                    // B3 (P_sh + nbT_sh + rsum visible)
  if (tid < 16) {
    float s = rsum_sh[0][tid];
    #pragma unroll
    for (int w = 1; w < 8; ++w) s += rsum_sh[w][tid];
    f_sh[tid] = (mx_sh[tid] > -1e37f) ? 1.0f / s : 0.0f;
  }

  // ---- MFMA aggregation (mapping verified in R2 kernel) ----
  const int nt = wv & 3, kh = wv >> 2;
  const int arow = lane & 15, agrp = lane >> 4;
  const int bcol = nt * 16 + (lane & 15);

  f32x4 C = {0.f, 0.f, 0.f, 0.f};
  #pragma unroll
  for (int ks = 0; ks < 8; ++ks) {
    const int jb = kh * 256 + ks * 32 + agrp * 8;
    short8 afr = *(const short8*)&P_sh[arow][jb];
    short8 bfr = *(const short8*)&nbT_sh[bcol][jb];
    C = __builtin_amdgcn_mfma_f32_16x16x32_bf16(afr, bfr, C, 0, 0, 0);
  }
  if (kh == 1) *(f32x4*)&red_sh[wv - 4][lane][0] = C;
  __syncthreads();                    // B4 (also publishes f_sh)
  if (kh == 0) {
    f32x4 P = *(const f32x4*)&red_sh[wv][lane][0];
    #pragma unroll
    for (int r = 0; r < 4; ++r) {
      const int rg = agrp * 4 + r;    // C/D: row = (lane>>4)*4 + reg
      const float f = f_sh[rg];
      const size_t adr = (nodeb + i0 + rg) * 64 + bcol;
      const float val = (C[r] + P[r]) * f + self_e[adr];
      out[adr] = (f > 0.f) ? val : 0.f;
    }
  }
}

// ---------------------------------------------------------------------------
extern "C" void kernel_launch(void* const* d_in, const int* in_sizes, int n_in,
                              void* d_out, int out_size, void* d_ws, size_t ws_size,
                              hipStream_t stream) {
  const float* nodes   = (const float*)d_in[0];
  const int*   edges   = (const int*)  d_in[1];
  const float* self_w1 = (const float*)d_in[2];
  const float* self_b1 = (const float*)d_in[3];
  const float* self_w2 = (const float*)d_in[4];
  const float* self_b2 = (const float*)d_in[5];
  const float* nb_w1   = (const float*)d_in[6];
  const float* nb_b1   = (const float*)d_in[7];
  const float* nb_w2   = (const float*)d_in[8];
  const float* nb_b2   = (const float*)d_in[9];
  const float* comb_w1 = (const float*)d_in[10];
  const float* comb_b1 = (const float*)d_in[11];
  const float* comb_w2 = (const float*)d_in[12];
  const float* comb_b2 = (const float*)d_in[13];

  float* ws     = (float*)d_ws;
  float* self_e = ws;                       // 262144
  float* ss     = ws + 262144;              // 262144
  float* snT    = ws + 524288;              // 262144  (transposed [b][k][j])
  float* sP     = ws + 786432;              // 4096
  float* sQ     = ws + 790528;              // 4096
  unsigned short* nbT = (unsigned short*)(ws + 794624);  // 262144 bf16

  node_mlps<<<512, 256, 0, stream>>>(
      nodes, self_w1, self_b1, self_w2, self_b2,
      nb_w1, nb_b1, nb_w2, nb_b2, comb_w1, comb_b1, comb_w2, comb_b2,
      self_e, ss, snT, sP, sQ, nbT);

  gat_attn<<<256, 512, 0, stream>>>(
      edges, comb_w2, self_e, ss, snT, sP, sQ, nbT, (float*)d_out);
}

// Round 5
// 38.864 us; speedup vs baseline: 1.0861x; 1.0861x over previous
//
#include <hip/hip_runtime.h>
#include <float.h>

typedef __attribute__((ext_vector_type(8))) short short8;
typedef __attribute__((ext_vector_type(4))) float f32x4;

#define SLOPE 0.2f
// leaky(t) = 0.6t + 0.4|t| for slope 0.2

__device__ __forceinline__ float leaky(float x) { return fmaxf(x, SLOPE * x); }

// f32 -> bf16 round-to-nearest-even
__device__ __forceinline__ unsigned short f2bf(float f) {
  unsigned u = __float_as_uint(f);
  return (unsigned short)((u + 0x7FFFu + ((u >> 16) & 1u)) >> 16);
}

// ---------------------------------------------------------------------------
// Kernel A: per-node MLPs + projections + rank-1 score terms + bf16 nb^T.
//   ss  = self_e @ comb_w1[:64] + comb_b1        (row-major)
//   sn  = nb_e   @ comb_w1[64:]                  (row-major)
//   sP  = 0.6*sum_k(w2_k*ss_k) + comb_b2 ; sQ = 0.6*sum_k(w2_k*sn_k)
//   nbT[b][h][j] = bf16(nb_e[b][j][h])           (MFMA B-operand layout)
// 512 blocks x 256 thr; 8 nodes/block; each wave owns 2 nodes.
// ---------------------------------------------------------------------------
__global__ __launch_bounds__(256) void node_mlps(
    const float* __restrict__ nodes,
    const float* __restrict__ self_w1, const float* __restrict__ self_b1,
    const float* __restrict__ self_w2, const float* __restrict__ self_b2,
    const float* __restrict__ nb_w1,   const float* __restrict__ nb_b1,
    const float* __restrict__ nb_w2,   const float* __restrict__ nb_b2,
    const float* __restrict__ comb_w1, const float* __restrict__ comb_b1,
    const float* __restrict__ comb_w2, const float* __restrict__ comb_b2,
    float* __restrict__ self_e,
    float* __restrict__ ss, float* __restrict__ sn,
    float* __restrict__ sP, float* __restrict__ sQ,
    unsigned short* __restrict__ nbT)
{
  __shared__ float x_sh[8][128];
  __shared__ float h_sh[8][64];
  __shared__ float e_sh[8][64];

  const int tid = threadIdx.x, lane = tid & 63, wv = tid >> 6;
  const int node0 = blockIdx.x * 8;
  const int bb = node0 >> 9;          // batch
  const int jloc = node0 & 511;       // batch-local node base

  ((float4*)&x_sh[0][0])[tid] = ((const float4*)(nodes + (size_t)node0 * 128))[tid];
  __syncthreads();

  const int la = wv * 2, lb = la + 1;
  const float w2lane = comb_w2[lane];
  const float cb2 = comb_b2[0];
  const float cb1 = comb_b1[lane];

  for (int p = 0; p < 2; ++p) {
    const float* w1 = p ? nb_w1 : self_w1;
    const float* b1 = p ? nb_b1 : self_b1;
    const float* w2 = p ? nb_w2 : self_w2;
    const float* b2 = p ? nb_b2 : self_b2;
    const float* cw = comb_w1 + (p ? 64 * 64 : 0);

    // ---- layer 1 ----
    float a0 = 0.f, a1 = 0.f, c0 = 0.f, c1 = 0.f;
    #pragma unroll 4
    for (int q = 0; q < 32; ++q) {
      float4 xa = *(const float4*)&x_sh[la][q * 4];
      float4 xb = *(const float4*)&x_sh[lb][q * 4];
      float w_0 = w1[(q * 4 + 0) * 64 + lane];
      float w_1 = w1[(q * 4 + 1) * 64 + lane];
      float w_2 = w1[(q * 4 + 2) * 64 + lane];
      float w_3 = w1[(q * 4 + 3) * 64 + lane];
      a0 += xa.x * w_0; a1 += xa.y * w_1; a0 += xa.z * w_2; a1 += xa.w * w_3;
      c0 += xb.x * w_0; c1 += xb.y * w_1; c0 += xb.z * w_2; c1 += xb.w * w_3;
    }
    {
      float bv = b1[lane];
      h_sh[la][lane] = leaky(a0 + a1 + bv);
      h_sh[lb][lane] = leaky(c0 + c1 + bv);
    }
    __syncthreads();

    // ---- layer 2 ----
    a0 = a1 = c0 = c1 = 0.f;
    #pragma unroll 4
    for (int q = 0; q < 16; ++q) {
      float4 ha = *(const float4*)&h_sh[la][q * 4];
      float4 hb = *(const float4*)&h_sh[lb][q * 4];
      float w_0 = w2[(q * 4 + 0) * 64 + lane];
      float w_1 = w2[(q * 4 + 1) * 64 + lane];
      float w_2 = w2[(q * 4 + 2) * 64 + lane];
      float w_3 = w2[(q * 4 + 3) * 64 + lane];
      a0 += ha.x * w_0; a1 += ha.y * w_1; a0 += ha.z * w_2; a1 += ha.w * w_3;
      c0 += hb.x * w_0; c1 += hb.y * w_1; c0 += hb.z * w_2; c1 += hb.w * w_3;
    }
    float e_a, e_b;
    {
      float bv = b2[lane];
      e_a = a0 + a1 + bv;
      e_b = c0 + c1 + bv;
    }
    e_sh[la][lane] = e_a;
    e_sh[lb][lane] = e_b;
    if (p == 0) {
      self_e[(size_t)(node0 + la) * 64 + lane] = e_a;
      self_e[(size_t)(node0 + lb) * 64 + lane] = e_b;
    }
    __syncthreads();

    // ---- projection ----
    a0 = a1 = c0 = c1 = 0.f;
    #pragma unroll 4
    for (int q = 0; q < 16; ++q) {
      float4 ea = *(const float4*)&e_sh[la][q * 4];
      float4 eb = *(const float4*)&e_sh[lb][q * 4];
      float w_0 = cw[(q * 4 + 0) * 64 + lane];
      float w_1 = cw[(q * 4 + 1) * 64 + lane];
      float w_2 = cw[(q * 4 + 2) * 64 + lane];
      float w_3 = cw[(q * 4 + 3) * 64 + lane];
      a0 += ea.x * w_0; a1 += ea.y * w_1; a0 += ea.z * w_2; a1 += ea.w * w_3;
      c0 += eb.x * w_0; c1 += eb.y * w_1; c0 += eb.z * w_2; c1 += eb.w * w_3;
    }
    float s_a = a0 + a1 + (p ? 0.f : cb1);
    float s_b = c0 + c1 + (p ? 0.f : cb1);
    {
      float* so = p ? sn : ss;
      so[(size_t)(node0 + la) * 64 + lane] = s_a;
      so[(size_t)(node0 + lb) * 64 + lane] = s_b;
    }
    float ra = w2lane * s_a, rb = w2lane * s_b;
    #pragma unroll
    for (int off = 32; off; off >>= 1) {
      ra += __shfl_xor(ra, off);
      rb += __shfl_xor(rb, off);
    }
    if (lane == 0) {
      float* po = p ? sQ : sP;
      float add = p ? 0.f : cb2;
      po[node0 + la] = 0.6f * ra + add;
      po[node0 + lb] = 0.6f * rb + add;
    }

    if (p == 1) {
      // nbT[b][h=lane][j]
      float v0 = e_sh[la][lane];
      float v1 = e_sh[lb][lane];
      unsigned pack = (unsigned)f2bf(v0) | ((unsigned)f2bf(v1) << 16);
      *(unsigned*)(nbT + ((size_t)(bb * 64 + lane) * 512 + jloc + la)) = pack;
    }
    __syncthreads();
  }
}

// ---------------------------------------------------------------------------
// Kernel B: 256 blocks (b = blk&7), 16 rows/block, 512 thr (8 waves).
// Wave wv owns rows {2wv, 2wv+1} end-to-end: scores in REGISTERS (8/row/lane),
// in-wave softmax (rows wholly wave-owned), bf16 P -> LDS, MFMA aggregation
// with B-fragments straight from global (L2-hot). Single-barrier double-
// buffered sn staging hides L2 latency under score compute.
// ---------------------------------------------------------------------------
__global__ __launch_bounds__(512) void gat_attn(
    const int* __restrict__ edges,
    const float* __restrict__ comb_w2,
    const float* __restrict__ self_e,
    const float* __restrict__ ss, const float* __restrict__ sn,
    const float* __restrict__ sP, const float* __restrict__ sQ,
    const unsigned short* __restrict__ nbT,
    float* __restrict__ out)
{
  __shared__ __align__(16) float sn_sh[2][64][68];          // 34.8 KB dbuf
  __shared__ __align__(16) unsigned short P_sh[16][520];    // 16.6 KB
  __shared__ __align__(16) float red_sh[4][64][4];          // 4 KB
  __shared__ float f_sh[16];

  const int tid = threadIdx.x, lane = tid & 63, wv = tid >> 6;
  const int b = blockIdx.x & 7, it = blockIdx.x >> 3;
  const int i0 = it * 16;
  const size_t nodeb = (size_t)b * 512;

  const int ra = wv * 2, rb = ra + 1;     // local rows (wave-owned)
  const int ia = i0 + ra, ib = ia + 1;    // batch-local rows

  // ---- prefetch: edge masks (bit-packed) + sQ ----
  unsigned em0 = 0, em1 = 0;
  float sQv[8];
  #pragma unroll
  for (int jt = 0; jt < 8; ++jt) {
    const int j = jt * 64 + lane;
    int2 e2 = *(const int2*)&edges[((size_t)(nodeb + j)) * 512 + ia];
    sQv[jt] = sQ[nodeb + j];
    em0 |= (e2.x != 0 ? 1u : 0u) << jt;
    em1 |= (e2.y != 0 ? 1u : 0u) << jt;
  }
  {
    const int d0 = ia - lane;             // self-loop: jt*64+lane == ia
    if (d0 >= 0 && (d0 & 63) == 0) em0 &= ~(1u << (d0 >> 6));
    const int d1 = ib - lane;
    if (d1 >= 0 && (d1 & 63) == 0) em1 &= ~(1u << (d1 >> 6));
  }

  // ---- hoist: w2p (0.4*w2), ss rows, sP scalars -> registers ----
  float4 w2p[16], sa0[16], sa1[16];
  {
    const float4* w2v = (const float4*)comb_w2;
    const float4* s0 = (const float4*)(ss + (nodeb + ia) * 64);
    const float4* s1 = (const float4*)(ss + (nodeb + ib) * 64);
    #pragma unroll
    for (int q = 0; q < 16; ++q) {
      float4 w = w2v[q];
      w2p[q] = make_float4(0.4f * w.x, 0.4f * w.y, 0.4f * w.z, 0.4f * w.w);
      sa0[q] = s0[q];
      sa1[q] = s1[q];
    }
  }
  const float sPa = sP[nodeb + ia], sPb = sP[nodeb + ib];

  // ---- phase 1: scores, double-buffered sn staging (1 barrier/tile) ----
  const int str = tid >> 4, stc = (tid & 15) * 4;
  const int str2 = (tid + 512) >> 4, stc2 = ((tid + 512) & 15) * 4;
  float4 st0, st1;
  {
    const float4* src = (const float4*)(sn + nodeb * 64);
    st0 = src[tid];
    st1 = src[tid + 512];
  }

  float msc0[8], msc1[8];
  int cur = 0;
  for (int jt = 0; jt < 8; ++jt) {
    *(float4*)&sn_sh[cur][str][stc] = st0;
    *(float4*)&sn_sh[cur][str2][stc2] = st1;
    if (jt < 7) {
      const float4* src = (const float4*)(sn + (nodeb + (jt + 1) * 64) * 64);
      st0 = src[tid];
      st1 = src[tid + 512];
    }
    __syncthreads();

    float acc0 = 0.f, acc1 = 0.f;
    #pragma unroll
    for (int q = 0; q < 16; ++q) {
      float4 v = *(const float4*)&sn_sh[cur][lane][q * 4];
      float4 w = w2p[q];
      float4 A = sa0[q];
      float4 Bv = sa1[q];
      acc0 += w.x * fabsf(A.x + v.x) + w.y * fabsf(A.y + v.y)
            + w.z * fabsf(A.z + v.z) + w.w * fabsf(A.w + v.w);
      acc1 += w.x * fabsf(Bv.x + v.x) + w.y * fabsf(Bv.y + v.y)
            + w.z * fabsf(Bv.z + v.z) + w.w * fabsf(Bv.w + v.w);
    }
    msc0[jt] = ((em0 >> jt) & 1u) ? acc0 + sPa + sQv[jt] : -FLT_MAX;
    msc1[jt] = ((em1 >> jt) & 1u) ? acc1 + sPb + sQv[jt] : -FLT_MAX;
    cur ^= 1;
  }

  // ---- phase 2: in-wave softmax (rows wholly owned by this wave) ----
  float m0 = msc0[0], m1 = msc1[0];
  #pragma unroll
  for (int jt = 1; jt < 8; ++jt) {
    m0 = fmaxf(m0, msc0[jt]);
    m1 = fmaxf(m1, msc1[jt]);
  }
  #pragma unroll
  for (int off = 32; off; off >>= 1) {
    m0 = fmaxf(m0, __shfl_xor(m0, off));
    m1 = fmaxf(m1, __shfl_xor(m1, off));
  }

  float s0 = 0.f, s1 = 0.f;
  #pragma unroll
  for (int jt = 0; jt < 8; ++jt) {
    const float e0 = __expf(msc0[jt] - m0);
    const float e1 = __expf(msc1[jt] - m1);
    P_sh[ra][jt * 64 + lane] = f2bf(e0);
    P_sh[rb][jt * 64 + lane] = f2bf(e1);
    s0 += e0;
    s1 += e1;
  }
  #pragma unroll
  for (int off = 32; off; off >>= 1) {
    s0 += __shfl_xor(s0, off);
    s1 += __shfl_xor(s1, off);
  }
  if (lane == 0) {
    f_sh[ra] = (m0 > -1e37f) ? 1.0f / s0 : 0.0f;
    f_sh[rb] = (m1 > -1e37f) ? 1.0f / s1 : 0.0f;
  }
  __syncthreads();                        // P_sh + f_sh visible to all waves

  // ---- phase 3: MFMA aggregation (A from LDS, B straight from global) ----
  const int nt = wv & 3, kh = wv >> 2;
  const int arow = lane & 15, agrp = lane >> 4;
  const int bcol = nt * 16 + (lane & 15);
  const unsigned short* nbrow = nbT + ((size_t)(b * 64 + bcol)) * 512;

  f32x4 C = {0.f, 0.f, 0.f, 0.f};
  #pragma unroll
  for (int ks = 0; ks < 8; ++ks) {
    const int jb = kh * 256 + ks * 32 + agrp * 8;
    short8 afr = *(const short8*)&P_sh[arow][jb];
    short8 bfr = *(const short8*)(nbrow + jb);
    C = __builtin_amdgcn_mfma_f32_16x16x32_bf16(afr, bfr, C, 0, 0, 0);
  }
  if (kh == 1) *(f32x4*)&red_sh[wv - 4][lane][0] = C;
  __syncthreads();
  if (kh == 0) {
    f32x4 P = *(const f32x4*)&red_sh[wv][lane][0];
    #pragma unroll
    for (int r = 0; r < 4; ++r) {
      const int rg = agrp * 4 + r;        // C/D: row = (lane>>4)*4 + reg
      const float f = f_sh[rg];
      const size_t adr = (nodeb + i0 + rg) * 64 + bcol;
      const float val = (C[r] + P[r]) * f + self_e[adr];
      out[adr] = (f > 0.f) ? val : 0.f;
    }
  }
}

// ---------------------------------------------------------------------------
extern "C" void kernel_launch(void* const* d_in, const int* in_sizes, int n_in,
                              void* d_out, int out_size, void* d_ws, size_t ws_size,
                              hipStream_t stream) {
  const float* nodes   = (const float*)d_in[0];
  const int*   edges   = (const int*)  d_in[1];
  const float* self_w1 = (const float*)d_in[2];
  const float* self_b1 = (const float*)d_in[3];
  const float* self_w2 = (const float*)d_in[4];
  const float* self_b2 = (const float*)d_in[5];
  const float* nb_w1   = (const float*)d_in[6];
  const float* nb_b1   = (const float*)d_in[7];
  const float* nb_w2   = (const float*)d_in[8];
  const float* nb_b2   = (const float*)d_in[9];
  const float* comb_w1 = (const float*)d_in[10];
  const float* comb_b1 = (const float*)d_in[11];
  const float* comb_w2 = (const float*)d_in[12];
  const float* comb_b2 = (const float*)d_in[13];

  float* ws     = (float*)d_ws;
  float* self_e = ws;                       // 262144
  float* ss     = ws + 262144;              // 262144
  float* sn     = ws + 524288;              // 262144 (row-major [b][j][k])
  float* sP     = ws + 786432;              // 4096
  float* sQ     = ws + 790528;              // 4096
  unsigned short* nbT = (unsigned short*)(ws + 794624);  // 262144 bf16

  node_mlps<<<512, 256, 0, stream>>>(
      nodes, self_w1, self_b1, self_w2, self_b2,
      nb_w1, nb_b1, nb_w2, nb_b2, comb_w1, comb_b1, comb_w2, comb_b2,
      self_e, ss, sn, sP, sQ, nbT);

  gat_attn<<<256, 512, 0, stream>>>(
      edges, comb_w2, self_e, ss, sn, sP, sQ, nbT, (float*)d_out);
}